// Round 5
// baseline (779.196 us; speedup 1.0000x reference)
//
#include <hip/hip_runtime.h>

#define FIN 64
#define HID 256
#define DEMB 128
#define NLAYERS 3

typedef __attribute__((ext_vector_type(8))) short bf16x8;
typedef __attribute__((ext_vector_type(4))) float f32x4;

__device__ inline short f2bf(float x) {               // RNE fp32 -> bf16 bits
    unsigned u = __float_as_uint(x);
    u += 0x7fff + ((u >> 16) & 1);
    return (short)(u >> 16);
}
__device__ inline float bf2f(short h) {
    return __uint_as_float(((unsigned)(unsigned short)h) << 16);
}

// Packed activation layout ("rowpack"): per row r a 1KB block of 512 shorts:
//   h of col c at  r*512 + (c>>3)*8 + (c&7)
//   l of col c at  r*512 + 256 + (c>>3)*8 + (c&7)
// MFMA A-fragment (k-slab g = c>>3) is the 16B chunk r*512 + g*8.

// ---------------- small graph-prep kernels ----------------

__global__ __launch_bounds__(256) void zero_kernel(int* counts, int n, float* pool_sum, int* pool_max) {
    int i = blockIdx.x * 256 + threadIdx.x;
    if (i < n) counts[i] = 0;
    if (i < HID) { pool_sum[i] = 0.0f; pool_max[i] = 0; }
}

__global__ __launch_bounds__(256) void hist_kernel(const int* __restrict__ ei, int E, int* __restrict__ counts) {
    int e = blockIdx.x * 256 + threadIdx.x;
    if (e < E) atomicAdd(&counts[ei[E + e]], 1);
}

// partial sums per 1024-chunk + dinv fused
__global__ __launch_bounds__(256) void scan_partial(const int* __restrict__ counts, int n,
                                                    int* __restrict__ chunkSums, float* __restrict__ dinv) {
    __shared__ int s[256];
    int t = threadIdx.x, base = blockIdx.x * 1024;
    int sum = 0;
#pragma unroll
    for (int j = 0; j < 4; j++) {
        int i = base + t * 4 + j;
        if (i < n) {
            int c = counts[i];
            sum += c;
            dinv[i] = rsqrtf((float)(c + 1));   // +1 self-loop, always > 0
        }
    }
    s[t] = sum; __syncthreads();
    for (int off = 128; off > 0; off >>= 1) { if (t < off) s[t] += s[t + off]; __syncthreads(); }
    if (t == 0) chunkSums[blockIdx.x] = s[0];
}

// wave-parallel exclusive scan over <=64 chunk sums
__global__ void scan_sums(int* cs, int nch) {
    int l = threadIdx.x;          // 64 threads
    int orig = (l < nch) ? cs[l] : 0;
    int v = orig;
    for (int off = 1; off < 64; off <<= 1) {
        int x = __shfl_up(v, off, 64);
        if (l >= off) v += x;
    }
    if (l < nch) cs[l] = v - orig;   // exclusive
}

__global__ __launch_bounds__(256) void scan_final(const int* __restrict__ counts, int n,
                                                  const int* __restrict__ chunkOff, int* __restrict__ row_ptr,
                                                  int* __restrict__ cursor) {
    __shared__ int s[256];
    int t = threadIdx.x, base = blockIdx.x * 1024;
    int v[4]; int sum = 0;
#pragma unroll
    for (int j = 0; j < 4; j++) { int i = base + t * 4 + j; v[j] = (i < n) ? counts[i] : 0; sum += v[j]; }
    s[t] = sum; __syncthreads();
    for (int off = 1; off < 256; off <<= 1) {
        int x = (t >= off) ? s[t - off] : 0;
        __syncthreads();
        s[t] += x;
        __syncthreads();
    }
    int run = chunkOff[blockIdx.x] + (s[t] - sum);
#pragma unroll
    for (int j = 0; j < 4; j++) {
        int i = base + t * 4 + j;
        if (i < n) {
            row_ptr[i] = run; cursor[i] = run; run += v[j];
            if (i == n - 1) row_ptr[n] = run;
        }
    }
}

__global__ __launch_bounds__(256) void fill_kernel(const int* __restrict__ ei, int E,
                                                   int* __restrict__ cursor, int* __restrict__ adj) {
    int e = blockIdx.x * 256 + threadIdx.x;
    if (e < E) {
        int s = ei[e], d = ei[E + e];
        int p = atomicAdd(&cursor[d], 1);
        adj[p] = s;
    }
}

// ---------------- weight packing: all 5 matrices in one launch ----------------
// element (k,n) -> P[ ((k>>3)*256 + n)*8 + (k&7) ]  (B-side keeps slab-major;
// weights are tiny and L2-resident, read layout is frag-contiguous)

__global__ __launch_bounds__(256) void pack_all(const float* __restrict__ W1, const float* __restrict__ W2,
                                                const float* __restrict__ Wc,
                                                short* __restrict__ PH, short* __restrict__ PL) {
    int b = blockIdx.x, n = threadIdx.x;
    const float* src; int k; size_t dst;
    if (b < 64) { src = W1; k = b; dst = 0; }
    else {
        int m = (b - 64) >> 8; k = (b - 64) & 255;
        src = (m == 0) ? W2 : (Wc + (size_t)(m - 1) * 65536);
        dst = 16384 + (size_t)m * 65536;
    }
    float w = src[(size_t)k * 256 + n];
    short h = f2bf(w);
    short l = f2bf(w - bf2f(h));
    int o = ((k >> 3) * 256 + n) * 8 + (k & 7);
    PH[dst + o] = h; PL[dst + o] = l;
}

// ---------------- split-bf16 MFMA GEMM, fp32 A (convert in kernel) ------------
// BM=64, BN=256, 4 waves, BK=32. OUTP: write rowpack split-bf16 activation.

template<int K, bool RELU, bool BIAS, bool OUTP>
__global__ __launch_bounds__(256) void gemm_conv(const float* __restrict__ A,
                                                 const short* __restrict__ PBh, const short* __restrict__ PBl,
                                                 const float* __restrict__ bias,
                                                 float* __restrict__ Cf, short* __restrict__ Cp,
                                                 int M) {
    __shared__ short AhL[4][64][8];   // [g][row][i] : k = g*8+i within step
    __shared__ short AlL[4][64][8];
    int t = threadIdx.x;
    int lane = t & 63, wave = t >> 6;
    int brow = blockIdx.x * 64;
    int bcol = wave * 64;
    int lr = lane & 15, lg = lane >> 4;
    f32x4 acc[4][4] = {};

    constexpr int NS = K / 32;
    float4 a_pre[2];
#pragma unroll
    for (int l = 0; l < 2; l++) {
        int lin = t + l * 256;
        int r = lin >> 3, kq = (lin & 7) * 4;
        int row = brow + r;
        a_pre[l] = (row < M) ? *(const float4*)(A + (size_t)row * K + kq)
                             : make_float4(0.f, 0.f, 0.f, 0.f);
    }

    for (int s = 0; s < NS; ++s) {
#pragma unroll
        for (int l = 0; l < 2; l++) {
            int lin = t + l * 256;
            int r = lin >> 3, kq = (lin & 7) * 4;
            int g = kq >> 3, i0 = kq & 7;
            float4 v = a_pre[l];
            short h0 = f2bf(v.x), h1 = f2bf(v.y), h2 = f2bf(v.z), h3 = f2bf(v.w);
            short e0 = f2bf(v.x - bf2f(h0)), e1 = f2bf(v.y - bf2f(h1));
            short e2 = f2bf(v.z - bf2f(h2)), e3 = f2bf(v.w - bf2f(h3));
            uint2 hw, lw;
            hw.x = (unsigned short)h0 | ((unsigned)(unsigned short)h1 << 16);
            hw.y = (unsigned short)h2 | ((unsigned)(unsigned short)h3 << 16);
            lw.x = (unsigned short)e0 | ((unsigned)(unsigned short)e1 << 16);
            lw.y = (unsigned short)e2 | ((unsigned)(unsigned short)e3 << 16);
            *(uint2*)&AhL[g][r][i0] = hw;
            *(uint2*)&AlL[g][r][i0] = lw;
        }
        const short* pbh = PBh + ((size_t)(s * 4 + lg) * 256 + bcol + lr) * 8;
        const short* pbl = PBl + ((size_t)(s * 4 + lg) * 256 + bcol + lr) * 8;
        bf16x8 bh[4], bl[4];
#pragma unroll
        for (int ni = 0; ni < 4; ni++) {
            bh[ni] = *(const bf16x8*)(pbh + ni * 128);
            bl[ni] = *(const bf16x8*)(pbl + ni * 128);
        }
        if (s + 1 < NS) {
#pragma unroll
            for (int l = 0; l < 2; l++) {
                int lin = t + l * 256;
                int r = lin >> 3, kq = (lin & 7) * 4;
                int row = brow + r;
                a_pre[l] = (row < M) ? *(const float4*)(A + (size_t)row * K + (s + 1) * 32 + kq)
                                     : make_float4(0.f, 0.f, 0.f, 0.f);
            }
        }
        __syncthreads();
        bf16x8 ah[4], al[4];
#pragma unroll
        for (int mi = 0; mi < 4; mi++) {
            ah[mi] = *(bf16x8*)&AhL[lg][mi * 16 + lr][0];
            al[mi] = *(bf16x8*)&AlL[lg][mi * 16 + lr][0];
        }
#pragma unroll
        for (int mi = 0; mi < 4; mi++)
#pragma unroll
            for (int ni = 0; ni < 4; ni++) {
                acc[mi][ni] = __builtin_amdgcn_mfma_f32_16x16x32_bf16(ah[mi], bh[ni], acc[mi][ni], 0, 0, 0);
                acc[mi][ni] = __builtin_amdgcn_mfma_f32_16x16x32_bf16(ah[mi], bl[ni], acc[mi][ni], 0, 0, 0);
                acc[mi][ni] = __builtin_amdgcn_mfma_f32_16x16x32_bf16(al[mi], bh[ni], acc[mi][ni], 0, 0, 0);
            }
        if (s + 1 < NS) __syncthreads();
    }

#pragma unroll
    for (int ni = 0; ni < 4; ni++) {
        int col = bcol + ni * 16 + lr;
        float bv = BIAS ? bias[col] : 0.f;
#pragma unroll
        for (int mi = 0; mi < 4; mi++)
#pragma unroll
            for (int j = 0; j < 4; j++) {
                int row = brow + mi * 16 + lg * 4 + j;
                if (row < M) {
                    float o = acc[mi][ni][j] + bv;
                    if (RELU) o = fmaxf(o, 0.f);
                    if (OUTP) {
                        short hh = f2bf(o);
                        short hl = f2bf(o - bf2f(hh));
                        size_t off = (size_t)row * 512 + (col >> 3) * 8 + (col & 7);
                        Cp[off] = hh; Cp[off + 256] = hl;
                    } else {
                        Cf[(size_t)row * 256 + col] = o;
                    }
                }
            }
    }
}

// ---------------- pure-MFMA GEMM, rowpack split-bf16 A (no LDS, no barriers) ---
// C[M,256] = A @ B, A rowpack fragment-order, out fp32 row-major.

__global__ __launch_bounds__(256) void gemm_packedA(const short* __restrict__ AP,
                                                    const short* __restrict__ PBh, const short* __restrict__ PBl,
                                                    float* __restrict__ C, int M) {
    int t = threadIdx.x;
    int lane = t & 63, wave = t >> 6;
    int brow = blockIdx.x * 64;
    int bcol = wave * 64;
    int lr = lane & 15, lg = lane >> 4;
    f32x4 acc[4][4] = {};

#pragma unroll
    for (int s = 0; s < 8; ++s) {
        int slab = s * 4 + lg;
        bf16x8 ah[4], al[4], bh[4], bl[4];
#pragma unroll
        for (int mi = 0; mi < 4; mi++) {
            size_t rb = (size_t)(brow + lr + mi * 16) * 512 + slab * 8;
            ah[mi] = *(const bf16x8*)(AP + rb);
            al[mi] = *(const bf16x8*)(AP + rb + 256);
        }
        const short* pbh = PBh + ((size_t)slab * 256 + bcol + lr) * 8;
        const short* pbl = PBl + ((size_t)slab * 256 + bcol + lr) * 8;
#pragma unroll
        for (int ni = 0; ni < 4; ni++) {
            bh[ni] = *(const bf16x8*)(pbh + ni * 128);
            bl[ni] = *(const bf16x8*)(pbl + ni * 128);
        }
#pragma unroll
        for (int mi = 0; mi < 4; mi++)
#pragma unroll
            for (int ni = 0; ni < 4; ni++) {
                acc[mi][ni] = __builtin_amdgcn_mfma_f32_16x16x32_bf16(ah[mi], bh[ni], acc[mi][ni], 0, 0, 0);
                acc[mi][ni] = __builtin_amdgcn_mfma_f32_16x16x32_bf16(ah[mi], bl[ni], acc[mi][ni], 0, 0, 0);
                acc[mi][ni] = __builtin_amdgcn_mfma_f32_16x16x32_bf16(al[mi], bh[ni], acc[mi][ni], 0, 0, 0);
            }
    }

#pragma unroll
    for (int ni = 0; ni < 4; ni++) {
        int col = bcol + ni * 16 + lr;
#pragma unroll
        for (int mi = 0; mi < 4; mi++)
#pragma unroll
            for (int j = 0; j < 4; j++) {
                int row = brow + mi * 16 + lg * 4 + j;
                if (row < M) C[(size_t)row * 256 + col] = acc[mi][ni][j];
            }
    }
}

// ---------------- GCN aggregation: one wave per dst node, rowpack output ------
// out[v] = relu( dv * ( dv*m[v] + sum_e dinv[src]*m[src] ) + bias ) -> rowpack

__global__ __launch_bounds__(256) void aggregate(const float* __restrict__ m, const int* __restrict__ row_ptr,
                                                 const int* __restrict__ adj, const float* __restrict__ dinv,
                                                 const float* __restrict__ bias,
                                                 short* __restrict__ outP, int n) {
    int v = blockIdx.x * 4 + (threadIdx.x >> 6);
    if (v >= n) return;
    int lane = threadIdx.x & 63;
    float dv = dinv[v];
    float4 mv = *(const float4*)(m + (size_t)v * HID + lane * 4);
    float4 acc = make_float4(dv * mv.x, dv * mv.y, dv * mv.z, dv * mv.w);
    int e = row_ptr[v], end = row_ptr[v + 1];

    for (; e + 8 <= end; e += 8) {
        int s[8]; float w[8]; float4 mm[8];
#pragma unroll
        for (int j = 0; j < 8; j++) s[j] = adj[e + j];
#pragma unroll
        for (int j = 0; j < 8; j++) mm[j] = *(const float4*)(m + (size_t)s[j] * HID + lane * 4);
#pragma unroll
        for (int j = 0; j < 8; j++) w[j] = dinv[s[j]];
#pragma unroll
        for (int j = 0; j < 8; j++) {
            acc.x = fmaf(w[j], mm[j].x, acc.x); acc.y = fmaf(w[j], mm[j].y, acc.y);
            acc.z = fmaf(w[j], mm[j].z, acc.z); acc.w = fmaf(w[j], mm[j].w, acc.w);
        }
    }
    for (; e < end; e++) {
        int s0 = adj[e];
        float w0 = dinv[s0];
        float4 m0 = *(const float4*)(m + (size_t)s0 * HID + lane * 4);
        acc.x = fmaf(w0, m0.x, acc.x); acc.y = fmaf(w0, m0.y, acc.y);
        acc.z = fmaf(w0, m0.z, acc.z); acc.w = fmaf(w0, m0.w, acc.w);
    }
    float4 b = *(const float4*)(bias + lane * 4);
    float4 o;
    o.x = fmaxf(fmaf(dv, acc.x, b.x), 0.f);
    o.y = fmaxf(fmaf(dv, acc.y, b.y), 0.f);
    o.z = fmaxf(fmaf(dv, acc.z, b.z), 0.f);
    o.w = fmaxf(fmaf(dv, acc.w, b.w), 0.f);

    // rowpack: cols c = lane*4 + j -> slab = lane>>1, i0 = (lane&1)*4
    short h0 = f2bf(o.x), h1 = f2bf(o.y), h2 = f2bf(o.z), h3 = f2bf(o.w);
    short l0 = f2bf(o.x - bf2f(h0)), l1 = f2bf(o.y - bf2f(h1));
    short l2 = f2bf(o.z - bf2f(h2)), l3 = f2bf(o.w - bf2f(h3));
    uint2 hw, lw;
    hw.x = (unsigned short)h0 | ((unsigned)(unsigned short)h1 << 16);
    hw.y = (unsigned short)h2 | ((unsigned)(unsigned short)h3 << 16);
    lw.x = (unsigned short)l0 | ((unsigned)(unsigned short)l1 << 16);
    lw.y = (unsigned short)l2 | ((unsigned)(unsigned short)l3 << 16);
    size_t off = (size_t)v * 512 + (lane >> 1) * 8 + (lane & 1) * 4;
    *(uint2*)(outP + off) = hw;           // h half (512B/row)
    *(uint2*)(outP + off + 256) = lw;     // l half
}

// ---------------- pooling (mean + max over rows) from rowpack h ---------------

__global__ __launch_bounds__(256) void pool_packed(const short* __restrict__ P, int n,
                                                   float* __restrict__ pool_sum, int* __restrict__ pool_max) {
    int t = threadIdx.x;  // column
    int so = (t >> 3) * 8 + (t & 7);
    int chunk = (n + gridDim.x - 1) / gridDim.x;
    int r0 = blockIdx.x * chunk, r1 = min(n, r0 + chunk);
    float s = 0.f, mx = 0.f;  // h >= 0 post-relu
    for (int r = r0; r < r1; r++) {
        size_t a = (size_t)r * 512 + so;
        float v = bf2f(P[a]) + bf2f(P[a + 256]);
        s += v;
        mx = fmaxf(mx, v);
    }
    atomicAdd(&pool_sum[t], s);
    atomicMax(&pool_max[t], __float_as_int(mx));  // valid: all values >= 0
}

// ---------------- final MLP head (single block) ----------------

__global__ __launch_bounds__(256) void mlp_head(const float* __restrict__ pool_sum, const int* __restrict__ pool_max,
                                                const float* __restrict__ Wp1, const float* __restrict__ bp1,
                                                const float* __restrict__ Wp2, const float* __restrict__ bp2,
                                                float* __restrict__ out, float invn) {
    __shared__ float g[2 * HID];
    __shared__ float hid[HID];
    int t = threadIdx.x;
    g[t] = pool_sum[t] * invn;
    g[HID + t] = __int_as_float(pool_max[t]);
    __syncthreads();
    float acc = bp1[t];
#pragma unroll 8
    for (int j = 0; j < 2 * HID; j++) acc = fmaf(g[j], Wp1[j * HID + t], acc);
    hid[t] = fmaxf(acc, 0.f);
    __syncthreads();
    if (t < DEMB) {
        float a2 = bp2[t];
#pragma unroll 8
        for (int j = 0; j < HID; j++) a2 = fmaf(hid[j], Wp2[j * DEMB + t], a2);
        out[t] = a2;
    }
}

// ---------------- launcher ----------------

extern "C" void kernel_launch(void* const* d_in, const int* in_sizes, int n_in,
                              void* d_out, int out_size, void* d_ws, size_t ws_size,
                              hipStream_t stream) {
    const float* x   = (const float*)d_in[0];
    const int*   ei  = (const int*)d_in[1];
    const float* W1  = (const float*)d_in[2];
    const float* b1  = (const float*)d_in[3];
    const float* W2  = (const float*)d_in[4];
    const float* b2  = (const float*)d_in[5];
    const float* Wc  = (const float*)d_in[6];
    const float* bc  = (const float*)d_in[7];
    const float* Wp1 = (const float*)d_in[8];
    const float* bp1 = (const float*)d_in[9];
    const float* Wp2 = (const float*)d_in[10];
    const float* bp2 = (const float*)d_in[11];
    float* out = (float*)d_out;

    int N = in_sizes[0] / FIN;
    int E = in_sizes[1] / 2;
    int gb = (N + 63) / 64;
    int R  = gb * 64;                    // padded row count for packed activations

    // workspace carve
    float* tmp     = (float*)d_ws;                       // [N, 256] fp32 (aggregate input)
    short* actP    = (short*)(tmp + (size_t)N * HID);    // [R, 512] shorts rowpack (h|l)
    int*   counts  = (int*)(actP + (size_t)R * 512);     // [N]
    int*   row_ptr = counts + N;                         // [N+1]
    int*   cursor  = row_ptr + (N + 1);                  // [N]
    int*   adj     = cursor + N;                         // [E]
    float* dinvp   = (float*)(adj + E);                  // [N]
    float* pool_sum = dinvp + N;                         // [HID]
    int*   pool_max = (int*)(pool_sum + HID);            // [HID]
    int*   chunkSums = pool_max + HID;                   // [<=64]
    short* PH = (short*)((((uintptr_t)(chunkSums + 64)) + 15) & ~(uintptr_t)15);
    short* PL = PH + 278528;
    const int oW1 = 0, oW2 = 16384, oC0 = 81920, oC1 = 147456, oC2 = 212992;

    int nch = (N + 1023) / 1024;
    int nb256 = (N + 255) / 256;
    int eb256 = (E + 255) / 256;

    zero_kernel<<<nb256, 256, 0, stream>>>(counts, N, pool_sum, pool_max);
    hist_kernel<<<eb256, 256, 0, stream>>>(ei, E, counts);
    scan_partial<<<nch, 256, 0, stream>>>(counts, N, chunkSums, dinvp);
    scan_sums<<<1, 64, 0, stream>>>(chunkSums, nch);
    scan_final<<<nch, 256, 0, stream>>>(counts, N, chunkSums, row_ptr, cursor);
    fill_kernel<<<eb256, 256, 0, stream>>>(ei, E, cursor, adj);

    pack_all<<<64 + 4 * 256, 256, 0, stream>>>(W1, W2, Wc, PH, PL);

    // encoder: tmp = relu(x@W1+b1) [fp32 out]; actP = tmp@W2+b2 [rowpack out]
    gemm_conv<FIN, true, true, false><<<gb, 256, 0, stream>>>(x, PH + oW1, PL + oW1, b1, tmp, nullptr, N);
    gemm_conv<HID, false, true, true><<<gb, 256, 0, stream>>>(tmp, PH + oW2, PL + oW2, b2, nullptr, actP, N);

    // GCN layers: tmp = actP@Wc (pure MFMA), actP = agg(tmp) rowpack
    const int oC[3] = {oC0, oC1, oC2};
    for (int L = 0; L < NLAYERS; L++) {
        gemm_packedA<<<gb, 256, 0, stream>>>(actP, PH + oC[L], PL + oC[L], tmp, N);
        aggregate<<<(N + 3) / 4, 256, 0, stream>>>(tmp, row_ptr, adj, dinvp, bc + (size_t)L * HID, actP, N);
    }

    // pooling + head
    pool_packed<<<256, 256, 0, stream>>>(actP, N, pool_sum, pool_max);
    mlp_head<<<1, 256, 0, stream>>>(pool_sum, pool_max, Wp1, bp1, Wp2, bp2, out, 1.0f / (float)N);
}

// Round 6
// 706.398 us; speedup vs baseline: 1.1031x; 1.1031x over previous
//
#include <hip/hip_runtime.h>

#define FIN 64
#define HID 256
#define DEMB 128
#define NLAYERS 3

typedef __attribute__((ext_vector_type(8))) short bf16x8;
typedef __attribute__((ext_vector_type(4))) float f32x4;

__device__ inline short f2bf(float x) {               // RNE fp32 -> bf16 bits
    unsigned u = __float_as_uint(x);
    u += 0x7fff + ((u >> 16) & 1);
    return (short)(u >> 16);
}
__device__ inline float bf2f(short h) {
    return __uint_as_float(((unsigned)(unsigned short)h) << 16);
}

// Packed activation layout: SLAB-MAJOR (GEMM-read-optimal).
//   h of (row, col) at  APh[ ((col>>3)*R + row)*8 + (col&7) ]
//   l array at APh + R*256.
// A-fragment for MFMA slab g: 16B chunk (g*R + row)*8 — 16 lanes (rows) read
// 256B contiguous. Aggregate writes go through an LDS transpose so global
// stores are full 64B lines.

// ---------------- small graph-prep kernels ----------------

__global__ __launch_bounds__(256) void zero_kernel(int* counts, int n, float* pool_sum, int* pool_max) {
    int i = blockIdx.x * 256 + threadIdx.x;
    if (i < n) counts[i] = 0;
    if (i < HID) { pool_sum[i] = 0.0f; pool_max[i] = 0; }
}

__global__ __launch_bounds__(256) void hist_kernel(const int* __restrict__ ei, int E, int* __restrict__ counts) {
    int e = blockIdx.x * 256 + threadIdx.x;
    if (e < E) atomicAdd(&counts[ei[E + e]], 1);
}

// partial sums per 1024-chunk + dinv fused
__global__ __launch_bounds__(256) void scan_partial(const int* __restrict__ counts, int n,
                                                    int* __restrict__ chunkSums, float* __restrict__ dinv) {
    __shared__ int s[256];
    int t = threadIdx.x, base = blockIdx.x * 1024;
    int sum = 0;
#pragma unroll
    for (int j = 0; j < 4; j++) {
        int i = base + t * 4 + j;
        if (i < n) {
            int c = counts[i];
            sum += c;
            dinv[i] = rsqrtf((float)(c + 1));   // +1 self-loop, always > 0
        }
    }
    s[t] = sum; __syncthreads();
    for (int off = 128; off > 0; off >>= 1) { if (t < off) s[t] += s[t + off]; __syncthreads(); }
    if (t == 0) chunkSums[blockIdx.x] = s[0];
}

// wave-parallel exclusive scan over <=64 chunk sums
__global__ void scan_sums(int* cs, int nch) {
    int l = threadIdx.x;          // 64 threads
    int orig = (l < nch) ? cs[l] : 0;
    int v = orig;
    for (int off = 1; off < 64; off <<= 1) {
        int x = __shfl_up(v, off, 64);
        if (l >= off) v += x;
    }
    if (l < nch) cs[l] = v - orig;   // exclusive
}

__global__ __launch_bounds__(256) void scan_final(const int* __restrict__ counts, int n,
                                                  const int* __restrict__ chunkOff, int* __restrict__ row_ptr,
                                                  int* __restrict__ cursor) {
    __shared__ int s[256];
    int t = threadIdx.x, base = blockIdx.x * 1024;
    int v[4]; int sum = 0;
#pragma unroll
    for (int j = 0; j < 4; j++) { int i = base + t * 4 + j; v[j] = (i < n) ? counts[i] : 0; sum += v[j]; }
    s[t] = sum; __syncthreads();
    for (int off = 1; off < 256; off <<= 1) {
        int x = (t >= off) ? s[t - off] : 0;
        __syncthreads();
        s[t] += x;
        __syncthreads();
    }
    int run = chunkOff[blockIdx.x] + (s[t] - sum);
#pragma unroll
    for (int j = 0; j < 4; j++) {
        int i = base + t * 4 + j;
        if (i < n) {
            row_ptr[i] = run; cursor[i] = run; run += v[j];
            if (i == n - 1) row_ptr[n] = run;
        }
    }
}

__global__ __launch_bounds__(256) void fill_kernel(const int* __restrict__ ei, int E,
                                                   int* __restrict__ cursor, int* __restrict__ adj) {
    int e = blockIdx.x * 256 + threadIdx.x;
    if (e < E) {
        int s = ei[e], d = ei[E + e];
        int p = atomicAdd(&cursor[d], 1);
        adj[p] = s;
    }
}

// ---------------- weight packing: all 5 matrices in one launch ----------------
// element (k,n) -> P[ ((k>>3)*256 + n)*8 + (k&7) ]

__global__ __launch_bounds__(256) void pack_all(const float* __restrict__ W1, const float* __restrict__ W2,
                                                const float* __restrict__ Wc,
                                                short* __restrict__ PH, short* __restrict__ PL) {
    int b = blockIdx.x, n = threadIdx.x;
    const float* src; int k; size_t dst;
    if (b < 64) { src = W1; k = b; dst = 0; }
    else {
        int m = (b - 64) >> 8; k = (b - 64) & 255;
        src = (m == 0) ? W2 : (Wc + (size_t)(m - 1) * 65536);
        dst = 16384 + (size_t)m * 65536;
    }
    float w = src[(size_t)k * 256 + n];
    short h = f2bf(w);
    short l = f2bf(w - bf2f(h));
    int o = ((k >> 3) * 256 + n) * 8 + (k & 7);
    PH[dst + o] = h; PL[dst + o] = l;
}

// ---------------- split-bf16 MFMA GEMM, fp32 A (convert in kernel) ------------
// BM=64, BN=256, 4 waves, BK=32. OUTP: write slab-major packed activation.

template<int K, bool RELU, bool BIAS, bool OUTP>
__global__ __launch_bounds__(256) void gemm_conv(const float* __restrict__ A,
                                                 const short* __restrict__ PBh, const short* __restrict__ PBl,
                                                 const float* __restrict__ bias,
                                                 float* __restrict__ Cf, short* __restrict__ Cp,
                                                 int M, int R) {
    __shared__ short AhL[4][64][8];   // [g][row][i] : k = g*8+i within step
    __shared__ short AlL[4][64][8];
    int t = threadIdx.x;
    int lane = t & 63, wave = t >> 6;
    int brow = blockIdx.x * 64;
    int bcol = wave * 64;
    int lr = lane & 15, lg = lane >> 4;
    f32x4 acc[4][4] = {};

    constexpr int NS = K / 32;
    float4 a_pre[2];
#pragma unroll
    for (int l = 0; l < 2; l++) {
        int lin = t + l * 256;
        int r = lin >> 3, kq = (lin & 7) * 4;
        int row = brow + r;
        a_pre[l] = (row < M) ? *(const float4*)(A + (size_t)row * K + kq)
                             : make_float4(0.f, 0.f, 0.f, 0.f);
    }

    for (int s = 0; s < NS; ++s) {
#pragma unroll
        for (int l = 0; l < 2; l++) {
            int lin = t + l * 256;
            int r = lin >> 3, kq = (lin & 7) * 4;
            int g = kq >> 3, i0 = kq & 7;
            float4 v = a_pre[l];
            short h0 = f2bf(v.x), h1 = f2bf(v.y), h2 = f2bf(v.z), h3 = f2bf(v.w);
            short e0 = f2bf(v.x - bf2f(h0)), e1 = f2bf(v.y - bf2f(h1));
            short e2 = f2bf(v.z - bf2f(h2)), e3 = f2bf(v.w - bf2f(h3));
            uint2 hw, lw;
            hw.x = (unsigned short)h0 | ((unsigned)(unsigned short)h1 << 16);
            hw.y = (unsigned short)h2 | ((unsigned)(unsigned short)h3 << 16);
            lw.x = (unsigned short)e0 | ((unsigned)(unsigned short)e1 << 16);
            lw.y = (unsigned short)e2 | ((unsigned)(unsigned short)e3 << 16);
            *(uint2*)&AhL[g][r][i0] = hw;
            *(uint2*)&AlL[g][r][i0] = lw;
        }
        const short* pbh = PBh + ((size_t)(s * 4 + lg) * 256 + bcol + lr) * 8;
        const short* pbl = PBl + ((size_t)(s * 4 + lg) * 256 + bcol + lr) * 8;
        bf16x8 bh[4], bl[4];
#pragma unroll
        for (int ni = 0; ni < 4; ni++) {
            bh[ni] = *(const bf16x8*)(pbh + ni * 128);
            bl[ni] = *(const bf16x8*)(pbl + ni * 128);
        }
        if (s + 1 < NS) {
#pragma unroll
            for (int l = 0; l < 2; l++) {
                int lin = t + l * 256;
                int r = lin >> 3, kq = (lin & 7) * 4;
                int row = brow + r;
                a_pre[l] = (row < M) ? *(const float4*)(A + (size_t)row * K + (s + 1) * 32 + kq)
                                     : make_float4(0.f, 0.f, 0.f, 0.f);
            }
        }
        __syncthreads();
        bf16x8 ah[4], al[4];
#pragma unroll
        for (int mi = 0; mi < 4; mi++) {
            ah[mi] = *(bf16x8*)&AhL[lg][mi * 16 + lr][0];
            al[mi] = *(bf16x8*)&AlL[lg][mi * 16 + lr][0];
        }
#pragma unroll
        for (int mi = 0; mi < 4; mi++)
#pragma unroll
            for (int ni = 0; ni < 4; ni++) {
                acc[mi][ni] = __builtin_amdgcn_mfma_f32_16x16x32_bf16(ah[mi], bh[ni], acc[mi][ni], 0, 0, 0);
                acc[mi][ni] = __builtin_amdgcn_mfma_f32_16x16x32_bf16(ah[mi], bl[ni], acc[mi][ni], 0, 0, 0);
                acc[mi][ni] = __builtin_amdgcn_mfma_f32_16x16x32_bf16(al[mi], bh[ni], acc[mi][ni], 0, 0, 0);
            }
        if (s + 1 < NS) __syncthreads();
    }

    short* Cpl = OUTP ? (Cp + (size_t)R * 256) : nullptr;
#pragma unroll
    for (int ni = 0; ni < 4; ni++) {
        int col = bcol + ni * 16 + lr;
        float bv = BIAS ? bias[col] : 0.f;
#pragma unroll
        for (int mi = 0; mi < 4; mi++)
#pragma unroll
            for (int j = 0; j < 4; j++) {
                int row = brow + mi * 16 + lg * 4 + j;
                if (row < M) {
                    float o = acc[mi][ni][j] + bv;
                    if (RELU) o = fmaxf(o, 0.f);
                    if (OUTP) {
                        short hh = f2bf(o);
                        short hl = f2bf(o - bf2f(hh));
                        size_t off = ((size_t)(col >> 3) * R + row) * 8 + (col & 7);
                        Cp[off] = hh; Cpl[off] = hl;
                    } else {
                        Cf[(size_t)row * 256 + col] = o;
                    }
                }
            }
    }
}

// ---------------- pure-MFMA GEMM, slab-major packed A (no LDS, no barriers) ----
// C[M,256] = A @ B, out fp32 row-major.

__global__ __launch_bounds__(256) void gemm_packedA(const short* __restrict__ AP,
                                                    const short* __restrict__ PBh, const short* __restrict__ PBl,
                                                    float* __restrict__ C, int M, int R) {
    int t = threadIdx.x;
    int lane = t & 63, wave = t >> 6;
    int brow = blockIdx.x * 64;
    int bcol = wave * 64;
    int lr = lane & 15, lg = lane >> 4;
    const short* APl = AP + (size_t)R * 256;
    f32x4 acc[4][4] = {};

#pragma unroll
    for (int s = 0; s < 8; ++s) {
        int slab = s * 4 + lg;
        size_t abase = ((size_t)slab * R + brow + lr) * 8;
        bf16x8 ah[4], al[4], bh[4], bl[4];
#pragma unroll
        for (int mi = 0; mi < 4; mi++) {
            ah[mi] = *(const bf16x8*)(AP + abase + mi * 128);
            al[mi] = *(const bf16x8*)(APl + abase + mi * 128);
        }
        const short* pbh = PBh + ((size_t)slab * 256 + bcol + lr) * 8;
        const short* pbl = PBl + ((size_t)slab * 256 + bcol + lr) * 8;
#pragma unroll
        for (int ni = 0; ni < 4; ni++) {
            bh[ni] = *(const bf16x8*)(pbh + ni * 128);
            bl[ni] = *(const bf16x8*)(pbl + ni * 128);
        }
#pragma unroll
        for (int mi = 0; mi < 4; mi++)
#pragma unroll
            for (int ni = 0; ni < 4; ni++) {
                acc[mi][ni] = __builtin_amdgcn_mfma_f32_16x16x32_bf16(ah[mi], bh[ni], acc[mi][ni], 0, 0, 0);
                acc[mi][ni] = __builtin_amdgcn_mfma_f32_16x16x32_bf16(ah[mi], bl[ni], acc[mi][ni], 0, 0, 0);
                acc[mi][ni] = __builtin_amdgcn_mfma_f32_16x16x32_bf16(al[mi], bh[ni], acc[mi][ni], 0, 0, 0);
            }
    }

#pragma unroll
    for (int ni = 0; ni < 4; ni++) {
        int col = bcol + ni * 16 + lr;
#pragma unroll
        for (int mi = 0; mi < 4; mi++)
#pragma unroll
            for (int j = 0; j < 4; j++) {
                int row = brow + mi * 16 + lg * 4 + j;
                if (row < M) C[(size_t)row * 256 + col] = acc[mi][ni][j];
            }
    }
}

// ---------------- GCN aggregation: one wave per dst node -----------------------
// out[v] = relu( dv * ( dv*m[v] + sum_e dinv[src]*m[src] ) + bias )
// -> slab-major packed, via LDS transpose so stores are full 64B lines.

__global__ __launch_bounds__(256) void aggregate(const float* __restrict__ m, const int* __restrict__ row_ptr,
                                                 const int* __restrict__ adj, const float* __restrict__ dinv,
                                                 const float* __restrict__ bias,
                                                 short* __restrict__ outP, int n, int R) {
    __shared__ short Lh[4][256];
    __shared__ short Ll[4][256];
    int t = threadIdx.x;
    int wv = t >> 6, lane = t & 63;
    int v0 = blockIdx.x * 4;
    int v = v0 + wv;

    if (v < n) {
        float dv = dinv[v];
        float4 mv = *(const float4*)(m + (size_t)v * HID + lane * 4);
        float4 acc = make_float4(dv * mv.x, dv * mv.y, dv * mv.z, dv * mv.w);
        int e = row_ptr[v], end = row_ptr[v + 1];

        for (; e + 8 <= end; e += 8) {
            int s[8]; float w[8]; float4 mm[8];
#pragma unroll
            for (int j = 0; j < 8; j++) s[j] = adj[e + j];
#pragma unroll
            for (int j = 0; j < 8; j++) mm[j] = *(const float4*)(m + (size_t)s[j] * HID + lane * 4);
#pragma unroll
            for (int j = 0; j < 8; j++) w[j] = dinv[s[j]];
#pragma unroll
            for (int j = 0; j < 8; j++) {
                acc.x = fmaf(w[j], mm[j].x, acc.x); acc.y = fmaf(w[j], mm[j].y, acc.y);
                acc.z = fmaf(w[j], mm[j].z, acc.z); acc.w = fmaf(w[j], mm[j].w, acc.w);
            }
        }
        for (; e < end; e++) {
            int s0 = adj[e];
            float w0 = dinv[s0];
            float4 m0 = *(const float4*)(m + (size_t)s0 * HID + lane * 4);
            acc.x = fmaf(w0, m0.x, acc.x); acc.y = fmaf(w0, m0.y, acc.y);
            acc.z = fmaf(w0, m0.z, acc.z); acc.w = fmaf(w0, m0.w, acc.w);
        }
        float4 b = *(const float4*)(bias + lane * 4);
        float4 o;
        o.x = fmaxf(fmaf(dv, acc.x, b.x), 0.f);
        o.y = fmaxf(fmaf(dv, acc.y, b.y), 0.f);
        o.z = fmaxf(fmaf(dv, acc.z, b.z), 0.f);
        o.w = fmaxf(fmaf(dv, acc.w, b.w), 0.f);

        short h0 = f2bf(o.x), h1 = f2bf(o.y), h2 = f2bf(o.z), h3 = f2bf(o.w);
        short l0 = f2bf(o.x - bf2f(h0)), l1 = f2bf(o.y - bf2f(h1));
        short l2 = f2bf(o.z - bf2f(h2)), l3 = f2bf(o.w - bf2f(h3));
        uint2 hw, lw;
        hw.x = (unsigned short)h0 | ((unsigned)(unsigned short)h1 << 16);
        hw.y = (unsigned short)h2 | ((unsigned)(unsigned short)h3 << 16);
        lw.x = (unsigned short)l0 | ((unsigned)(unsigned short)l1 << 16);
        lw.y = (unsigned short)l2 | ((unsigned)(unsigned short)l3 << 16);
        *(uint2*)&Lh[wv][lane * 4] = hw;     // cols lane*4..lane*4+3
        *(uint2*)&Ll[wv][lane * 4] = lw;
    }
    __syncthreads();

    // cooperative write-out: thread t -> 16B chunk; 4 consecutive threads = one
    // full 64B line at ((slab*R + v0)*8).  part: 0=h, 1=l.
    int vi = t & 3, slab = (t >> 2) & 31, part = t >> 7;
    int vv = v0 + vi;
    if (vv < n) {
        const short* src = (part ? Ll[vi] : Lh[vi]) + slab * 8;
        short* dst = outP + (part ? (size_t)R * 256 : 0) + ((size_t)slab * R + vv) * 8;
        *(uint4*)dst = *(const uint4*)src;
    }
}

// ---------------- pooling (mean + max over rows) from slab-major packed -------

__global__ __launch_bounds__(256) void pool_packed(const short* __restrict__ Ph, int n, int R,
                                                   float* __restrict__ pool_sum, int* __restrict__ pool_max) {
    int t = threadIdx.x;  // column
    const short* Pl = Ph + (size_t)R * 256;
    size_t base = (size_t)(t >> 3) * R * 8 + (t & 7);
    int chunk = (n + gridDim.x - 1) / gridDim.x;
    int r0 = blockIdx.x * chunk, r1 = min(n, r0 + chunk);
    float s = 0.f, mx = 0.f;  // h >= 0 post-relu
    for (int r = r0; r < r1; r++) {
        size_t a = base + (size_t)r * 8;
        float v = bf2f(Ph[a]) + bf2f(Pl[a]);
        s += v;
        mx = fmaxf(mx, v);
    }
    atomicAdd(&pool_sum[t], s);
    atomicMax(&pool_max[t], __float_as_int(mx));  // valid: all values >= 0
}

// ---------------- final MLP head (single block) ----------------

__global__ __launch_bounds__(256) void mlp_head(const float* __restrict__ pool_sum, const int* __restrict__ pool_max,
                                                const float* __restrict__ Wp1, const float* __restrict__ bp1,
                                                const float* __restrict__ Wp2, const float* __restrict__ bp2,
                                                float* __restrict__ out, float invn) {
    __shared__ float g[2 * HID];
    __shared__ float hid[HID];
    int t = threadIdx.x;
    g[t] = pool_sum[t] * invn;
    g[HID + t] = __int_as_float(pool_max[t]);
    __syncthreads();
    float acc = bp1[t];
#pragma unroll 8
    for (int j = 0; j < 2 * HID; j++) acc = fmaf(g[j], Wp1[j * HID + t], acc);
    hid[t] = fmaxf(acc, 0.f);
    __syncthreads();
    if (t < DEMB) {
        float a2 = bp2[t];
#pragma unroll 8
        for (int j = 0; j < HID; j++) a2 = fmaf(hid[j], Wp2[j * DEMB + t], a2);
        out[t] = a2;
    }
}

// ---------------- launcher ----------------

extern "C" void kernel_launch(void* const* d_in, const int* in_sizes, int n_in,
                              void* d_out, int out_size, void* d_ws, size_t ws_size,
                              hipStream_t stream) {
    const float* x   = (const float*)d_in[0];
    const int*   ei  = (const int*)d_in[1];
    const float* W1  = (const float*)d_in[2];
    const float* b1  = (const float*)d_in[3];
    const float* W2  = (const float*)d_in[4];
    const float* b2  = (const float*)d_in[5];
    const float* Wc  = (const float*)d_in[6];
    const float* bc  = (const float*)d_in[7];
    const float* Wp1 = (const float*)d_in[8];
    const float* bp1 = (const float*)d_in[9];
    const float* Wp2 = (const float*)d_in[10];
    const float* bp2 = (const float*)d_in[11];
    float* out = (float*)d_out;

    int N = in_sizes[0] / FIN;
    int E = in_sizes[1] / 2;
    int gb = (N + 63) / 64;
    int R  = gb * 64;                    // padded row count for packed activations

    // workspace carve
    float* tmp     = (float*)d_ws;                       // [N, 256] fp32 (aggregate input)
    short* actP    = (short*)(tmp + (size_t)N * HID);    // [R*256]*2 shorts slab-major (h|l)
    int*   counts  = (int*)(actP + (size_t)R * 512);     // [N]
    int*   row_ptr = counts + N;                         // [N+1]
    int*   cursor  = row_ptr + (N + 1);                  // [N]
    int*   adj     = cursor + N;                         // [E]
    float* dinvp   = (float*)(adj + E);                  // [N]
    float* pool_sum = dinvp + N;                         // [HID]
    int*   pool_max = (int*)(pool_sum + HID);            // [HID]
    int*   chunkSums = pool_max + HID;                   // [<=64]
    short* PH = (short*)((((uintptr_t)(chunkSums + 64)) + 15) & ~(uintptr_t)15);
    short* PL = PH + 278528;
    const int oW1 = 0, oW2 = 16384, oC0 = 81920, oC1 = 147456, oC2 = 212992;

    int nch = (N + 1023) / 1024;
    int nb256 = (N + 255) / 256;
    int eb256 = (E + 255) / 256;

    zero_kernel<<<nb256, 256, 0, stream>>>(counts, N, pool_sum, pool_max);
    hist_kernel<<<eb256, 256, 0, stream>>>(ei, E, counts);
    scan_partial<<<nch, 256, 0, stream>>>(counts, N, chunkSums, dinvp);
    scan_sums<<<1, 64, 0, stream>>>(chunkSums, nch);
    scan_final<<<nch, 256, 0, stream>>>(counts, N, chunkSums, row_ptr, cursor);
    fill_kernel<<<eb256, 256, 0, stream>>>(ei, E, cursor, adj);

    pack_all<<<64 + 4 * 256, 256, 0, stream>>>(W1, W2, Wc, PH, PL);

    // encoder: tmp = relu(x@W1+b1) [fp32 out]; actP = tmp@W2+b2 [packed out]
    gemm_conv<FIN, true, true, false><<<gb, 256, 0, stream>>>(x, PH + oW1, PL + oW1, b1, tmp, nullptr, N, R);
    gemm_conv<HID, false, true, true><<<gb, 256, 0, stream>>>(tmp, PH + oW2, PL + oW2, b2, nullptr, actP, N, R);

    // GCN layers: tmp = actP@Wc (pure MFMA), actP = agg(tmp) packed
    const int oC[3] = {oC0, oC1, oC2};
    for (int L = 0; L < NLAYERS; L++) {
        gemm_packedA<<<gb, 256, 0, stream>>>(actP, PH + oC[L], PL + oC[L], tmp, N, R);
        aggregate<<<(N + 3) / 4, 256, 0, stream>>>(tmp, row_ptr, adj, dinvp, bc + (size_t)L * HID, actP, N, R);
    }

    // pooling + head
    pool_packed<<<256, 256, 0, stream>>>(actP, N, R, pool_sum, pool_max);
    mlp_head<<<1, 256, 0, stream>>>(pool_sum, pool_max, Wp1, bp1, Wp2, bp2, out, 1.0f / (float)N);
}